// Round 2
// baseline (535.120 us; speedup 1.0000x reference)
//
#include <hip/hip_runtime.h>
#include <hip/hip_bf16.h>

// GCN 3-layer: h = GCNConv -> BN -> ReLU (x2) -> GCNConv -> +residual
// N=50000 nodes, E=800000 edges, D=128 channels, fp32.
//
// Strategy:
//   1. Build CSR (by dst) once per launch: histogram + single-block scan + fill.
//      Converts scatter-add (102M fp atomics/layer) into pull-based gather (0 fp atomics).
//   2. Per layer: LDS-tiled fp32 matmul (h = act @ W), then fused
//      aggregate+selfloop+bias+BN+ReLU kernel (one wave per node, float2/lane).
//   3. Layer 3 fuses bias + residual, writes d_out.
// All stream ops are plain kernel launches (graph-capture safe).

#define GCN_N 50000
#define GCN_E 800000
#define GCN_D 128

// ---------------------------------------------------------------- zero int buf
__global__ __launch_bounds__(256) void zero_kernel(int* __restrict__ p, int n) {
    int i = blockIdx.x * blockDim.x + threadIdx.x;
    if (i < n) p[i] = 0;
}

// ---------------------------------------------------------------- histogram
__global__ __launch_bounds__(256) void hist_kernel(const int* __restrict__ dst,
                                                   int* __restrict__ cnt, int nE) {
    int e = blockIdx.x * blockDim.x + threadIdx.x;
    if (e < nE) atomicAdd(&cnt[dst[e]], 1);
}

// ------------------------------------------------- single-block exclusive scan
// Also emits dinv[i] = rsqrt(deg_i + 1) and zeroes cnt for reuse as fill cursor.
__global__ __launch_bounds__(1024) void scan_kernel(int* __restrict__ cnt,
                                                    int* __restrict__ row_ptr,
                                                    float* __restrict__ dinv, int n) {
    __shared__ int wsum[16];
    __shared__ int s_run;
    int tid = threadIdx.x;
    int lane = tid & 63, wid = tid >> 6;
    if (tid == 0) s_run = 0;
    __syncthreads();
    const int CH = 4096;  // 1024 threads x 4 elements
    for (int base = 0; base < n; base += CH) {
        int i0 = base + tid * 4;
        int a0 = 0, a1 = 0, a2 = 0, a3 = 0;
        if (i0 + 0 < n) a0 = cnt[i0 + 0];
        if (i0 + 1 < n) a1 = cnt[i0 + 1];
        if (i0 + 2 < n) a2 = cnt[i0 + 2];
        if (i0 + 3 < n) a3 = cnt[i0 + 3];
        int tsum = a0 + a1 + a2 + a3;
        // inclusive wave scan of tsum
        int sc = tsum;
        #pragma unroll
        for (int off = 1; off < 64; off <<= 1) {
            int t = __shfl_up(sc, off);
            if (lane >= off) sc += t;
        }
        if (lane == 63) wsum[wid] = sc;
        __syncthreads();
        int woff = 0, ctot = 0;
        #pragma unroll
        for (int w = 0; w < 16; ++w) {
            int s = wsum[w];
            if (w < wid) woff += s;
            ctot += s;
        }
        int excl = s_run + woff + (sc - tsum);
        if (i0 + 0 < n) { row_ptr[i0 + 0] = excl;                dinv[i0 + 0] = rsqrtf((float)a0 + 1.f); cnt[i0 + 0] = 0; }
        if (i0 + 1 < n) { row_ptr[i0 + 1] = excl + a0;           dinv[i0 + 1] = rsqrtf((float)a1 + 1.f); cnt[i0 + 1] = 0; }
        if (i0 + 2 < n) { row_ptr[i0 + 2] = excl + a0 + a1;      dinv[i0 + 2] = rsqrtf((float)a2 + 1.f); cnt[i0 + 2] = 0; }
        if (i0 + 3 < n) { row_ptr[i0 + 3] = excl + a0 + a1 + a2; dinv[i0 + 3] = rsqrtf((float)a3 + 1.f); cnt[i0 + 3] = 0; }
        __syncthreads();
        if (tid == 0) s_run += ctot;
        __syncthreads();
    }
    if (tid == 0) row_ptr[n] = s_run;  // == E
}

// ---------------------------------------------------------------- CSR fill
__global__ __launch_bounds__(256) void fill_kernel(const int* __restrict__ src,
                                                   const int* __restrict__ dst,
                                                   const int* __restrict__ row_ptr,
                                                   int* __restrict__ cur,
                                                   const float* __restrict__ dinv,
                                                   int* __restrict__ esrc,
                                                   float* __restrict__ ecoef, int nE) {
    int e = blockIdx.x * blockDim.x + threadIdx.x;
    if (e >= nE) return;
    int d = dst[e], s = src[e];
    int pos = row_ptr[d] + atomicAdd(&cur[d], 1);
    esrc[pos] = s;
    ecoef[pos] = dinv[s] * dinv[d];
}

// ------------------------------------------------- fold BN into scale/shift
// out = (acc + b - m) * g*rsqrt(v+eps) + be  =  acc*scale + shift
__global__ void prep_kernel(const float* __restrict__ b, const float* __restrict__ g,
                            const float* __restrict__ be, const float* __restrict__ m,
                            const float* __restrict__ v, float* __restrict__ scale,
                            float* __restrict__ shift) {
    int c = threadIdx.x;
    float s = g[c] * rsqrtf(v[c] + 1e-5f);
    scale[c] = s;
    shift[c] = (b[c] - m[c]) * s + be[c];
}

// ---------------------------------------------------------------- matmul
// H[N,128] = A[N,128] @ W[128,128], fp32 vector ALU.
// Block: 256 threads (16x16), tile 64 rows x 128 cols, BK=64, per-thread 4x8.
__global__ __launch_bounds__(256) void mm_kernel(const float* __restrict__ A,
                                                 const float* __restrict__ W,
                                                 float* __restrict__ H, int n) {
    __shared__ float As[64][68];    // pad 68: 16B-aligned float4 stores, 2-way-max bank reads
    __shared__ float Bs[64][132];   // pad 132: 16B-aligned
    int tid = threadIdx.x;
    int tx = tid & 15;   // col group: 8 cols each
    int ty = tid >> 4;   // row group: 4 rows each
    int row0 = blockIdx.x * 64;
    float acc[4][8] = {};

    for (int k0 = 0; k0 < 128; k0 += 64) {
        // load A tile 64x64
        int ac = (tid & 15) * 4;
        int ar = tid >> 4;  // 0..15
        #pragma unroll
        for (int rr = 0; rr < 4; ++rr) {
            int r = ar + rr * 16;
            int gr = row0 + r;
            float4 v = make_float4(0.f, 0.f, 0.f, 0.f);
            if (gr < n) v = *(const float4*)&A[(size_t)gr * GCN_D + k0 + ac];
            *(float4*)&As[r][ac] = v;
        }
        // load W tile 64x128
        int bc = (tid & 31) * 4;
        int br = tid >> 5;  // 0..7
        #pragma unroll
        for (int rr = 0; rr < 8; ++rr) {
            int r = br + rr * 8;
            float4 v = *(const float4*)&W[(size_t)(k0 + r) * GCN_D + bc];
            *(float4*)&Bs[r][bc] = v;
        }
        __syncthreads();
        #pragma unroll
        for (int kk = 0; kk < 64; ++kk) {
            float a[4];
            #pragma unroll
            for (int m = 0; m < 4; ++m) a[m] = As[ty * 4 + m][kk];
            float4 b0 = *(const float4*)&Bs[kk][tx * 8];
            float4 b1 = *(const float4*)&Bs[kk][tx * 8 + 4];
            float b[8] = {b0.x, b0.y, b0.z, b0.w, b1.x, b1.y, b1.z, b1.w};
            #pragma unroll
            for (int m = 0; m < 4; ++m)
                #pragma unroll
                for (int q = 0; q < 8; ++q) acc[m][q] += a[m] * b[q];
        }
        __syncthreads();
    }
    #pragma unroll
    for (int m = 0; m < 4; ++m) {
        int gr = row0 + ty * 4 + m;
        if (gr < n) {
            *(float4*)&H[(size_t)gr * GCN_D + tx * 8] =
                make_float4(acc[m][0], acc[m][1], acc[m][2], acc[m][3]);
            *(float4*)&H[(size_t)gr * GCN_D + tx * 8 + 4] =
                make_float4(acc[m][4], acc[m][5], acc[m][6], acc[m][7]);
        }
    }
}

// ------------------------------------------------- fused aggregate + epilogue
// One wave per node; lane owns 2 channels (float2) -> 512B coalesced gather/edge.
// FINAL=0: out = relu(acc*scale + shift); FINAL=1: out = acc + b3 + x_res.
template <int FINAL>
__global__ __launch_bounds__(256) void agg_kernel(const float* __restrict__ h,
                                                  const int* __restrict__ row_ptr,
                                                  const int* __restrict__ esrc,
                                                  const float* __restrict__ ecoef,
                                                  const float* __restrict__ dinv,
                                                  const float* __restrict__ scale,
                                                  const float* __restrict__ shift,
                                                  const float* __restrict__ xres,
                                                  float* __restrict__ out, int n) {
    int wid = threadIdx.x >> 6, lane = threadIdx.x & 63;
    int node = blockIdx.x * 4 + wid;
    if (node >= n) return;
    int c0 = lane * 2;
    float di = dinv[node];
    float dd = di * di;
    float2 acc = *(const float2*)&h[(size_t)node * GCN_D + c0];
    acc.x *= dd;
    acc.y *= dd;
    int j = row_ptr[node], end = row_ptr[node + 1];
    // 2-way unroll: both gathers in flight together
    for (; j + 1 < end; j += 2) {
        int s0 = esrc[j];
        int s1 = esrc[j + 1];
        float w0 = ecoef[j];
        float w1 = ecoef[j + 1];
        float2 h0 = *(const float2*)&h[(size_t)s0 * GCN_D + c0];
        float2 h1 = *(const float2*)&h[(size_t)s1 * GCN_D + c0];
        acc.x += h0.x * w0 + h1.x * w1;
        acc.y += h0.y * w0 + h1.y * w1;
    }
    if (j < end) {
        int s0 = esrc[j];
        float w0 = ecoef[j];
        float2 h0 = *(const float2*)&h[(size_t)s0 * GCN_D + c0];
        acc.x += h0.x * w0;
        acc.y += h0.y * w0;
    }
    float2 o;
    if (FINAL) {
        float2 b = *(const float2*)&scale[c0];  // b3 passed via 'scale'
        float2 xr = *(const float2*)&xres[(size_t)node * GCN_D + c0];
        o.x = acc.x + b.x + xr.x;
        o.y = acc.y + b.y + xr.y;
    } else {
        float2 sc = *(const float2*)&scale[c0];
        float2 sh = *(const float2*)&shift[c0];
        o.x = fmaxf(acc.x * sc.x + sh.x, 0.f);
        o.y = fmaxf(acc.y * sc.y + sh.y, 0.f);
    }
    *(float2*)&out[(size_t)node * GCN_D + c0] = o;
}

// ---------------------------------------------------------------- launch
extern "C" void kernel_launch(void* const* d_in, const int* in_sizes, int n_in,
                              void* d_out, int out_size, void* d_ws, size_t ws_size,
                              hipStream_t stream) {
    (void)in_sizes; (void)n_in; (void)out_size; (void)ws_size;
    const int N = GCN_N, E = GCN_E, D = GCN_D;

    const float* x   = (const float*)d_in[0];
    const float* W1  = (const float*)d_in[1];
    const float* b1  = (const float*)d_in[2];
    const float* g1  = (const float*)d_in[3];
    const float* be1 = (const float*)d_in[4];
    const float* m1  = (const float*)d_in[5];
    const float* v1  = (const float*)d_in[6];
    const float* W2  = (const float*)d_in[7];
    const float* b2  = (const float*)d_in[8];
    const float* g2  = (const float*)d_in[9];
    const float* be2 = (const float*)d_in[10];
    const float* m2  = (const float*)d_in[11];
    const float* v2  = (const float*)d_in[12];
    const float* W3  = (const float*)d_in[13];
    const float* b3  = (const float*)d_in[14];
    const int* src   = (const int*)d_in[15];
    const int* dst   = (const int*)d_in[16];
    float* out = (float*)d_out;

    // workspace layout (all 4B types; base is 256B aligned)
    float* h      = (float*)d_ws;            // N*D
    float* act    = h + (size_t)N * D;       // N*D
    float* dinv   = act + (size_t)N * D;     // N
    int* cnt      = (int*)(dinv + N);        // N (histogram, then fill cursor)
    int* row_ptr  = cnt + N;                 // N+1
    int* esrc     = row_ptr + (N + 1);       // E
    float* ecoef  = (float*)(esrc + E);      // E
    float* scale1 = ecoef + E;               // 128
    float* shift1 = scale1 + D;              // 128
    float* scale2 = shift1 + D;              // 128
    float* shift2 = scale2 + D;              // 128

    // ---- CSR build (reused by all 3 layers)
    zero_kernel<<<(N + 255) / 256, 256, 0, stream>>>(cnt, N);
    hist_kernel<<<(E + 255) / 256, 256, 0, stream>>>(dst, cnt, E);
    scan_kernel<<<1, 1024, 0, stream>>>(cnt, row_ptr, dinv, N);
    fill_kernel<<<(E + 255) / 256, 256, 0, stream>>>(src, dst, row_ptr, cnt, dinv,
                                                     esrc, ecoef, E);
    prep_kernel<<<1, D, 0, stream>>>(b1, g1, be1, m1, v1, scale1, shift1);
    prep_kernel<<<1, D, 0, stream>>>(b2, g2, be2, m2, v2, scale2, shift2);

    int mm_grid = (N + 63) / 64;
    int agg_grid = (N + 3) / 4;

    // ---- layer 1
    mm_kernel<<<mm_grid, 256, 0, stream>>>(x, W1, h, N);
    agg_kernel<0><<<agg_grid, 256, 0, stream>>>(h, row_ptr, esrc, ecoef, dinv,
                                                scale1, shift1, nullptr, act, N);
    // ---- layer 2
    mm_kernel<<<mm_grid, 256, 0, stream>>>(act, W2, h, N);
    agg_kernel<0><<<agg_grid, 256, 0, stream>>>(h, row_ptr, esrc, ecoef, dinv,
                                                scale2, shift2, nullptr, act, N);
    // ---- layer 3 (+bias +residual, writes d_out)
    mm_kernel<<<mm_grid, 256, 0, stream>>>(act, W3, h, N);
    agg_kernel<1><<<agg_grid, 256, 0, stream>>>(h, row_ptr, esrc, ecoef, dinv,
                                                b3, nullptr, x, out, N);
}

// Round 3
// 473.289 us; speedup vs baseline: 1.1306x; 1.1306x over previous
//
#include <hip/hip_runtime.h>
#include <hip/hip_bf16.h>

// GCN 3-layer: h = GCNConv -> BN -> ReLU (x2) -> GCNConv -> +residual
// N=50000 nodes, E=800000 edges, D=128 channels, fp32.
//
// Round 3 changes (theory: agg is latency-bound on L3 gathers, not BW-bound):
//   - agg: 4-way edge unroll (4 gathers in flight), packed int2 edge meta
//     {src, coef} -> one 8B uniform load per edge, dual accumulator chains.
//   - CSR prefix sum: multi-block (reduce -> scan-sums -> scan-apply) instead
//     of single-block serial-chunk scan.
//   - mm / hist / fill / prep unchanged for clean attribution.

#define GCN_N 50000
#define GCN_E 800000
#define GCN_D 128

// ---------------------------------------------------------------- zero int buf
__global__ __launch_bounds__(256) void zero_kernel(int* __restrict__ p, int n) {
    int i = blockIdx.x * blockDim.x + threadIdx.x;
    if (i < n) p[i] = 0;
}

// ---------------------------------------------------------------- histogram
__global__ __launch_bounds__(256) void hist_kernel(const int* __restrict__ dst,
                                                   int* __restrict__ cnt, int nE) {
    int e = blockIdx.x * blockDim.x + threadIdx.x;
    if (e < nE) atomicAdd(&cnt[dst[e]], 1);
}

// ------------------------------------------------- multi-block prefix sum
// A: per-block (1024 elems) sums.  B: scan the 49 block sums.  C: apply.
__global__ __launch_bounds__(256) void block_reduce(const int* __restrict__ cnt,
                                                    int* __restrict__ bsum, int n) {
    int tid = threadIdx.x, lane = tid & 63, wid = tid >> 6;
    int i0 = blockIdx.x * 1024 + tid * 4;
    int s = 0;
    #pragma unroll
    for (int q = 0; q < 4; ++q)
        if (i0 + q < n) s += cnt[i0 + q];
    #pragma unroll
    for (int off = 32; off >= 1; off >>= 1) s += __shfl_xor(s, off);
    __shared__ int ws[4];
    if (lane == 0) ws[wid] = s;
    __syncthreads();
    if (tid == 0) bsum[blockIdx.x] = ws[0] + ws[1] + ws[2] + ws[3];
}

__global__ void scan_bsums(const int* __restrict__ bsum, int* __restrict__ boff,
                           int nb, int* __restrict__ row_last) {
    int lane = threadIdx.x;  // 64 threads
    int v = (lane < nb) ? bsum[lane] : 0;
    int sc = v;
    #pragma unroll
    for (int off = 1; off < 64; off <<= 1) {
        int t = __shfl_up(sc, off);
        if (lane >= off) sc += t;
    }
    if (lane < nb) boff[lane] = sc - v;
    if (lane == 63) *row_last = sc;  // row_ptr[N] = E
}

// writes row_ptr (exclusive scan), dinv = rsqrt(deg+1), zeroes cnt for fill.
__global__ __launch_bounds__(256) void scan_apply(const int* __restrict__ cnt_in,
                                                  const int* __restrict__ boff,
                                                  int* __restrict__ row_ptr,
                                                  float* __restrict__ dinv,
                                                  int* __restrict__ cnt_zero, int n) {
    __shared__ int wsum[4];
    int tid = threadIdx.x, lane = tid & 63, wid = tid >> 6;
    int i0 = blockIdx.x * 1024 + tid * 4;
    int a0 = 0, a1 = 0, a2 = 0, a3 = 0;
    if (i0 + 0 < n) a0 = cnt_in[i0 + 0];
    if (i0 + 1 < n) a1 = cnt_in[i0 + 1];
    if (i0 + 2 < n) a2 = cnt_in[i0 + 2];
    if (i0 + 3 < n) a3 = cnt_in[i0 + 3];
    int tsum = a0 + a1 + a2 + a3;
    int sc = tsum;
    #pragma unroll
    for (int off = 1; off < 64; off <<= 1) {
        int t = __shfl_up(sc, off);
        if (lane >= off) sc += t;
    }
    if (lane == 63) wsum[wid] = sc;
    __syncthreads();
    int woff = 0;
    #pragma unroll
    for (int w = 0; w < 4; ++w)
        if (w < wid) woff += wsum[w];
    int excl = boff[blockIdx.x] + woff + (sc - tsum);
    if (i0 + 0 < n) { row_ptr[i0 + 0] = excl;                dinv[i0 + 0] = rsqrtf((float)a0 + 1.f); cnt_zero[i0 + 0] = 0; }
    if (i0 + 1 < n) { row_ptr[i0 + 1] = excl + a0;           dinv[i0 + 1] = rsqrtf((float)a1 + 1.f); cnt_zero[i0 + 1] = 0; }
    if (i0 + 2 < n) { row_ptr[i0 + 2] = excl + a0 + a1;      dinv[i0 + 2] = rsqrtf((float)a2 + 1.f); cnt_zero[i0 + 2] = 0; }
    if (i0 + 3 < n) { row_ptr[i0 + 3] = excl + a0 + a1 + a2; dinv[i0 + 3] = rsqrtf((float)a3 + 1.f); cnt_zero[i0 + 3] = 0; }
}

// ---------------------------------------------------------------- CSR fill
// emeta[pos] = {src, bits(coef)} packed -> one 8B load per edge in agg.
__global__ __launch_bounds__(256) void fill_kernel(const int* __restrict__ src,
                                                   const int* __restrict__ dst,
                                                   const int* __restrict__ row_ptr,
                                                   int* __restrict__ cur,
                                                   const float* __restrict__ dinv,
                                                   int2* __restrict__ emeta, int nE) {
    int e = blockIdx.x * blockDim.x + threadIdx.x;
    if (e >= nE) return;
    int d = dst[e], s = src[e];
    int pos = row_ptr[d] + atomicAdd(&cur[d], 1);
    emeta[pos] = make_int2(s, __float_as_int(dinv[s] * dinv[d]));
}

// ------------------------------------------------- fold BN into scale/shift
__global__ void prep_kernel(const float* __restrict__ b, const float* __restrict__ g,
                            const float* __restrict__ be, const float* __restrict__ m,
                            const float* __restrict__ v, float* __restrict__ scale,
                            float* __restrict__ shift) {
    int c = threadIdx.x;
    float s = g[c] * rsqrtf(v[c] + 1e-5f);
    scale[c] = s;
    shift[c] = (b[c] - m[c]) * s + be[c];
}

// ---------------------------------------------------------------- matmul
// H[N,128] = A[N,128] @ W[128,128], fp32 vector ALU. (unchanged)
__global__ __launch_bounds__(256) void mm_kernel(const float* __restrict__ A,
                                                 const float* __restrict__ W,
                                                 float* __restrict__ H, int n) {
    __shared__ float As[64][68];
    __shared__ float Bs[64][132];
    int tid = threadIdx.x;
    int tx = tid & 15;
    int ty = tid >> 4;
    int row0 = blockIdx.x * 64;
    float acc[4][8] = {};

    for (int k0 = 0; k0 < 128; k0 += 64) {
        int ac = (tid & 15) * 4;
        int ar = tid >> 4;
        #pragma unroll
        for (int rr = 0; rr < 4; ++rr) {
            int r = ar + rr * 16;
            int gr = row0 + r;
            float4 v = make_float4(0.f, 0.f, 0.f, 0.f);
            if (gr < n) v = *(const float4*)&A[(size_t)gr * GCN_D + k0 + ac];
            *(float4*)&As[r][ac] = v;
        }
        int bc = (tid & 31) * 4;
        int br = tid >> 5;
        #pragma unroll
        for (int rr = 0; rr < 8; ++rr) {
            int r = br + rr * 8;
            float4 v = *(const float4*)&W[(size_t)(k0 + r) * GCN_D + bc];
            *(float4*)&Bs[r][bc] = v;
        }
        __syncthreads();
        #pragma unroll
        for (int kk = 0; kk < 64; ++kk) {
            float a[4];
            #pragma unroll
            for (int m = 0; m < 4; ++m) a[m] = As[ty * 4 + m][kk];
            float4 b0 = *(const float4*)&Bs[kk][tx * 8];
            float4 b1 = *(const float4*)&Bs[kk][tx * 8 + 4];
            float b[8] = {b0.x, b0.y, b0.z, b0.w, b1.x, b1.y, b1.z, b1.w};
            #pragma unroll
            for (int m = 0; m < 4; ++m)
                #pragma unroll
                for (int q = 0; q < 8; ++q) acc[m][q] += a[m] * b[q];
        }
        __syncthreads();
    }
    #pragma unroll
    for (int m = 0; m < 4; ++m) {
        int gr = row0 + ty * 4 + m;
        if (gr < n) {
            *(float4*)&H[(size_t)gr * GCN_D + tx * 8] =
                make_float4(acc[m][0], acc[m][1], acc[m][2], acc[m][3]);
            *(float4*)&H[(size_t)gr * GCN_D + tx * 8 + 4] =
                make_float4(acc[m][4], acc[m][5], acc[m][6], acc[m][7]);
        }
    }
}

// ------------------------------------------------- fused aggregate + epilogue
// One wave per node; lane owns 2 channels (float2). 4 gathers in flight.
// FINAL=0: out = relu(acc*scale + shift); FINAL=1: out = acc + b3 + x_res.
template <int FINAL>
__global__ __launch_bounds__(256) void agg_kernel(const float* __restrict__ h,
                                                  const int* __restrict__ row_ptr,
                                                  const int2* __restrict__ emeta,
                                                  const float* __restrict__ dinv,
                                                  const float* __restrict__ scale,
                                                  const float* __restrict__ shift,
                                                  const float* __restrict__ xres,
                                                  float* __restrict__ out, int n) {
    int wid = threadIdx.x >> 6, lane = threadIdx.x & 63;
    int node = blockIdx.x * 4 + wid;
    if (node >= n) return;
    int c0 = lane * 2;
    float di = dinv[node];
    float dd = di * di;
    float2 self = *(const float2*)&h[(size_t)node * GCN_D + c0];
    float ax = self.x * dd, ay = self.y * dd;   // chain A
    float bx = 0.f, by = 0.f;                   // chain B
    int j = row_ptr[node], end = row_ptr[node + 1];
    for (; j + 3 < end; j += 4) {
        int2 m0 = emeta[j + 0];
        int2 m1 = emeta[j + 1];
        int2 m2 = emeta[j + 2];
        int2 m3 = emeta[j + 3];
        float2 h0 = *(const float2*)&h[(size_t)m0.x * GCN_D + c0];
        float2 h1 = *(const float2*)&h[(size_t)m1.x * GCN_D + c0];
        float2 h2 = *(const float2*)&h[(size_t)m2.x * GCN_D + c0];
        float2 h3 = *(const float2*)&h[(size_t)m3.x * GCN_D + c0];
        float w0 = __int_as_float(m0.y), w1 = __int_as_float(m1.y);
        float w2 = __int_as_float(m2.y), w3 = __int_as_float(m3.y);
        ax += h0.x * w0 + h1.x * w1;
        ay += h0.y * w0 + h1.y * w1;
        bx += h2.x * w2 + h3.x * w3;
        by += h2.y * w2 + h3.y * w3;
    }
    for (; j < end; ++j) {
        int2 m = emeta[j];
        float w = __int_as_float(m.y);
        float2 hh = *(const float2*)&h[(size_t)m.x * GCN_D + c0];
        ax += hh.x * w;
        ay += hh.y * w;
    }
    float accx = ax + bx, accy = ay + by;
    float2 o;
    if (FINAL) {
        float2 b = *(const float2*)&scale[c0];  // b3 passed via 'scale'
        float2 xr = *(const float2*)&xres[(size_t)node * GCN_D + c0];
        o.x = accx + b.x + xr.x;
        o.y = accy + b.y + xr.y;
    } else {
        float2 sc = *(const float2*)&scale[c0];
        float2 sh = *(const float2*)&shift[c0];
        o.x = fmaxf(accx * sc.x + sh.x, 0.f);
        o.y = fmaxf(accy * sc.y + sh.y, 0.f);
    }
    *(float2*)&out[(size_t)node * GCN_D + c0] = o;
}

// ---------------------------------------------------------------- launch
extern "C" void kernel_launch(void* const* d_in, const int* in_sizes, int n_in,
                              void* d_out, int out_size, void* d_ws, size_t ws_size,
                              hipStream_t stream) {
    (void)in_sizes; (void)n_in; (void)out_size; (void)ws_size;
    const int N = GCN_N, E = GCN_E, D = GCN_D;

    const float* x   = (const float*)d_in[0];
    const float* W1  = (const float*)d_in[1];
    const float* b1  = (const float*)d_in[2];
    const float* g1  = (const float*)d_in[3];
    const float* be1 = (const float*)d_in[4];
    const float* m1  = (const float*)d_in[5];
    const float* v1  = (const float*)d_in[6];
    const float* W2  = (const float*)d_in[7];
    const float* b2  = (const float*)d_in[8];
    const float* g2  = (const float*)d_in[9];
    const float* be2 = (const float*)d_in[10];
    const float* m2  = (const float*)d_in[11];
    const float* v2  = (const float*)d_in[12];
    const float* W3  = (const float*)d_in[13];
    const float* b3  = (const float*)d_in[14];
    const int* src   = (const int*)d_in[15];
    const int* dst   = (const int*)d_in[16];
    float* out = (float*)d_out;

    // workspace layout
    float* h      = (float*)d_ws;            // N*D
    float* act    = h + (size_t)N * D;       // N*D
    float* dinv   = act + (size_t)N * D;     // N
    int* cnt      = (int*)(dinv + N);        // N
    int* row_ptr  = cnt + N;                 // N+1
    int2* emeta   = (int2*)(row_ptr + N + 2); // E (int2, 8B aligned: offset even)
    float* scale1 = (float*)(emeta + E);     // 128
    float* shift1 = scale1 + D;
    float* scale2 = shift1 + D;
    float* shift2 = scale2 + D;
    int* bsum     = (int*)(shift2 + D);      // 64
    int* boff     = bsum + 64;               // 64

    const int NB = (N + 1023) / 1024;  // 49 scan blocks

    // ---- CSR build (reused by all 3 layers)
    zero_kernel<<<(N + 255) / 256, 256, 0, stream>>>(cnt, N);
    hist_kernel<<<(E + 255) / 256, 256, 0, stream>>>(dst, cnt, E);
    block_reduce<<<NB, 256, 0, stream>>>(cnt, bsum, N);
    scan_bsums<<<1, 64, 0, stream>>>(bsum, boff, NB, &row_ptr[N]);
    scan_apply<<<NB, 256, 0, stream>>>(cnt, boff, row_ptr, dinv, cnt, N);
    fill_kernel<<<(E + 255) / 256, 256, 0, stream>>>(src, dst, row_ptr, cnt, dinv,
                                                     emeta, E);
    prep_kernel<<<1, D, 0, stream>>>(b1, g1, be1, m1, v1, scale1, shift1);
    prep_kernel<<<1, D, 0, stream>>>(b2, g2, be2, m2, v2, scale2, shift2);

    int mm_grid = (N + 63) / 64;
    int agg_grid = (N + 3) / 4;

    // ---- layer 1
    mm_kernel<<<mm_grid, 256, 0, stream>>>(x, W1, h, N);
    agg_kernel<0><<<agg_grid, 256, 0, stream>>>(h, row_ptr, emeta, dinv,
                                                scale1, shift1, nullptr, act, N);
    // ---- layer 2
    mm_kernel<<<mm_grid, 256, 0, stream>>>(act, W2, h, N);
    agg_kernel<0><<<agg_grid, 256, 0, stream>>>(h, row_ptr, emeta, dinv,
                                                scale2, shift2, nullptr, act, N);
    // ---- layer 3 (+bias +residual, writes d_out)
    mm_kernel<<<mm_grid, 256, 0, stream>>>(act, W3, h, N);
    agg_kernel<1><<<agg_grid, 256, 0, stream>>>(h, row_ptr, emeta, dinv,
                                                b3, nullptr, x, out, N);
}